// Round 7
// baseline (469.831 us; speedup 1.0000x reference)
//
#include <hip/hip_runtime.h>

// Problem constants
// B=8, C=512, H=W=64, HW=4096, NUM=64, CG=8, NC=19, OUT=512, ICAT=1024

typedef __attribute__((ext_vector_type(8))) unsigned short u16x8;
typedef __attribute__((ext_vector_type(8))) __bf16 bf16x8;
typedef __attribute__((ext_vector_type(4))) float f32x4;
typedef __attribute__((ext_vector_type(16))) float f32x16;

__device__ inline unsigned short f2bf(float f) {
    unsigned int u = __float_as_uint(f);
    u += 0x7fffu + ((u >> 16) & 1u);
    return (unsigned short)(u >> 16);
}

__device__ __forceinline__ void gload16(unsigned short* lds, const unsigned short* g) {
    __builtin_amdgcn_global_load_lds(
        (const __attribute__((address_space(1))) unsigned int*)g,
        (__attribute__((address_space(3))) unsigned int*)lds, 16, 0, 0);
}

// ---------------------------------------------------------------------------
// Repack bot_w [512][1024][3][3] f32 -> wt[tap][oc][ic] bf16.
// ---------------------------------------------------------------------------
__global__ __launch_bounds__(256) void repack_w(const float* __restrict__ w,
                                                unsigned short* __restrict__ wt) {
    __shared__ float buf[9216];
    const int oc = blockIdx.x;  // 512
    const int tid = threadIdx.x;
    const float* src = w + (size_t)oc * 9216;
    for (int i = tid; i < 9216; i += 256) buf[i] = src[i];
    __syncthreads();
#pragma unroll
    for (int t = 0; t < 9; ++t) {
        for (int i = tid; i < 1024; i += 256)
            wt[((size_t)t * 512 + oc) * 1024 + i] = f2bf(buf[i * 9 + t]);
    }
}

// ---------------------------------------------------------------------------
// front: fused decoder_map + fuse-partial + local-partial + x->bf16 cat.
// ---------------------------------------------------------------------------
__global__ __launch_bounds__(256) void front_kernel(
    const float* __restrict__ x, const float* __restrict__ dct,
    const float* __restrict__ w1, const float* __restrict__ gamma,
    const float* __restrict__ beta, const float* __restrict__ w2,
    const float* __restrict__ b2, const float* __restrict__ fuse_w,
    float* __restrict__ part, float* __restrict__ fpart,
    unsigned short* __restrict__ cat) {
    __shared__ __align__(16) float fgs[8][260];
    __shared__ __align__(16) float fms[19][260];
    __shared__ float sw1[64], sw2[152], sb2[19], sg[8], sb[8], sfw[64];
    const int bid = blockIdx.x;
    const int sp = bid >> 7;
    const int b = (bid >> 4) & 7;
    const int ch = bid & 15;
    const int tid = threadIdx.x;
    if (tid < 64) { sw1[tid] = w1[tid]; sfw[tid] = fuse_w[tid]; }
    if (tid < 152) sw2[tid] = w2[tid];
    if (tid < 19) sb2[tid] = b2[tid];
    if (tid < 8) { sg[tid] = gamma[tid]; sb[tid] = beta[tid]; }
    __syncthreads();
    const int p = ch * 256 + tid;
    const int kk = tid >> 3, cc = tid & 7;
    float facc[19];
#pragma unroll
    for (int k = 0; k < 19; ++k) facc[k] = 0.f;
    for (int nn = 0; nn < 16; ++nn) {
        const int n = sp * 16 + nn;
        float fg[8];
        u16x8 xw;
#pragma unroll
        for (int c = 0; c < 8; ++c) {
            const float xv = x[((size_t)(b * 512 + n * 8 + c)) * 4096 + p];
            fg[c] = xv * dct[((size_t)(n * 8 + c)) * 4096 + p];
            xw[c] = f2bf(xv);
            fgs[c][tid] = fg[c];
        }
        *(u16x8*)(cat + ((size_t)(b * 4096) + p) * 1024 + n * 8) = xw;
        float h1[8];
#pragma unroll
        for (int d = 0; d < 8; ++d) {
            float s = 0.f;
#pragma unroll
            for (int c = 0; c < 8; ++c) s = fmaf(sw1[d * 8 + c], fg[c], s);
            h1[d] = fmaxf(fmaf(s, sg[d], sb[d]), 0.f);
        }
        const float fw = sfw[n];
#pragma unroll
        for (int k = 0; k < 19; ++k) {
            float s = sb2[k];
#pragma unroll
            for (int d = 0; d < 8; ++d) s = fmaf(sw2[k * 8 + d], h1[d], s);
            fms[k][tid] = s;
            facc[k] = fmaf(fw, s, facc[k]);
        }
        __syncthreads();
        if (tid < 152) {
            float accv = 0.f;
#pragma unroll 8
            for (int p4 = 0; p4 < 256; p4 += 4) {
                const float4 a = *(const float4*)&fms[kk][p4];
                const float4 g4 = *(const float4*)&fgs[cc][p4];
                accv += a.x * g4.x + a.y * g4.y + a.z * g4.z + a.w * g4.w;
            }
            part[((size_t)((b * 64 + n) * 16) + ch) * 152 + tid] = accv;
        }
        __syncthreads();
    }
#pragma unroll
    for (int k = 0; k < 19; ++k)
        fpart[((size_t)(sp * 8 + b) * 19 + k) * 4096 + p] = facc[k];
}

__global__ __launch_bounds__(256) void fuse_reduce(
    const float* __restrict__ fpart, const float* __restrict__ fuse_b,
    float* __restrict__ out1) {
    const int i = blockIdx.x * 256 + threadIdx.x;  // 622592 total
    float s = fuse_b[0];
#pragma unroll
    for (int sp = 0; sp < 4; ++sp) s += fpart[(size_t)sp * 622592 + i];
    out1[i] = s;
}

// ---------------------------------------------------------------------------
// GCN
// ---------------------------------------------------------------------------
__global__ __launch_bounds__(256) void gcn_kernel(
    const float* __restrict__ part, const float* __restrict__ w1,
    const float* __restrict__ w2, float* __restrict__ local2) {
    __shared__ float L[9728];
    __shared__ float R[9728];
    __shared__ float sw1[4096];
    __shared__ float sw2[64];
    const int b = blockIdx.x;
    const int tid = threadIdx.x;
    for (int i = tid; i < 4096; i += 256) sw1[i] = w1[i];
    if (tid < 64) sw2[tid] = w2[tid];
    for (int i = tid; i < 9728; i += 256) {
        int n = i / 152, t = i - n * 152;
        float s = 0.f;
#pragma unroll
        for (int ch = 0; ch < 16; ++ch)
            s += part[((size_t)((b * 64 + n) * 16) + ch) * 152 + t];
        L[i] = s;
    }
    __syncthreads();
    for (int i = tid; i < 9728; i += 256) {
        int m = i / 152, t = i - m * 152;
        float g = 0.f;
        for (int n = 0; n < 64; ++n) g = fmaf(sw1[m * 64 + n], L[n * 152 + t], g);
        R[i] = fmaxf(g + L[i], 0.f);
    }
    __syncthreads();
    for (int i = tid; i < 9728; i += 256) {
        int n = i / 152, t = i - n * 152;
        int k = t >> 3, d = t & 7;
        float s = 0.f;
#pragma unroll
        for (int c = 0; c < 8; ++c) s = fmaf(R[n * 152 + k * 8 + c], sw2[d * 8 + c], s);
        local2[(size_t)b * 9728 + i] = s;
    }
}

// ---------------------------------------------------------------------------
// attention: per (b,n): softmax(x@L^T)@L -> cat upper half bf16
// ---------------------------------------------------------------------------
__global__ __launch_bounds__(256) void attn_kernel(
    const float* __restrict__ x, const float* __restrict__ local2,
    unsigned short* __restrict__ cat) {
    __shared__ float L[152];
    const int bn = blockIdx.x;  // 512
    const int b = bn >> 6, n = bn & 63;
    const int tid = threadIdx.x;
    if (tid < 152) L[tid] = local2[(size_t)bn * 152 + tid];
    __syncthreads();
    for (int i = 0; i < 16; ++i) {
        const int p = i * 256 + tid;
        float xv[8];
#pragma unroll
        for (int c = 0; c < 8; ++c)
            xv[c] = x[((size_t)(b * 512 + n * 8 + c)) * 4096 + p];
        float lg[19];
        float mx = -1e30f;
#pragma unroll
        for (int k = 0; k < 19; ++k) {
            float s = 0.f;
#pragma unroll
            for (int c = 0; c < 8; ++c) s = fmaf(xv[c], L[k * 8 + c], s);
            lg[k] = s;
            mx = fmaxf(mx, s);
        }
        float se = 0.f;
#pragma unroll
        for (int k = 0; k < 19; ++k) {
            lg[k] = __expf(lg[k] - mx);
            se += lg[k];
        }
        const float inv = 1.f / se;
        float ov[8];
#pragma unroll
        for (int c = 0; c < 8; ++c) ov[c] = 0.f;
#pragma unroll
        for (int k = 0; k < 19; ++k) {
#pragma unroll
            for (int c = 0; c < 8; ++c) ov[c] = fmaf(lg[k], L[k * 8 + c], ov[c]);
        }
        u16x8 w;
#pragma unroll
        for (int c = 0; c < 8; ++c) w[c] = f2bf(ov[c] * inv);
        *(u16x8*)(cat + ((size_t)(b * 4096) + p) * 1024 + 512 + n * 8) = w;
    }
}

// ---------------------------------------------------------------------------
// conv 3x3 SAME implicit GEMM, ic-major A-reuse (r6 structure) with MFMA
// shape 32x32x16 (was 16x16x32): halves MFMA instruction count and cuts
// per-tap ds_read_b128 from 40 to 24 per wave (both ks-pairs of A stay
// register-resident; B halves read once each).  Staging side + vmcnt
// ledger + 1 barrier/tap carried over VERBATIM from validated r6 kernel.
// Wave tile 128px x 64oc = 4 row-tiles x 2 col-tiles of 32x32.
// LDS: A 80KB + B 64KB = 144KB.
// ---------------------------------------------------------------------------
__global__ __launch_bounds__(512, 1) void conv_kernel(
    const unsigned short* __restrict__ cat, const unsigned short* __restrict__ wt,
    const unsigned short* __restrict__ zp,
    const float* __restrict__ gamma, const float* __restrict__ beta,
    float* __restrict__ out) {
    __shared__ __align__(16) unsigned short As[10 * 4096];  // 10 row-slots x 8KB
    __shared__ __align__(16) unsigned short Bs[2 * 16384];  // 2 slots x 32KB
    const int bid0 = blockIdx.x;                    // 256 blocks
    const int bid = (bid0 & 7) * 32 + (bid0 >> 3);  // XCD swizzle (bijective)
    const int mt = bid >> 1;                        // 128 M-tiles
    const int nt = bid & 1;                         // 2 N-tiles
    const int b = mt >> 4;
    const int pix0 = (mt & 15) * 256;
    const int y0 = (mt & 15) * 4;
    const int ocb = nt * 256;
    const int tid = threadIdx.x;
    const int w = tid >> 6;
    const int lane = tid & 63;
    const int l31 = lane & 31;
    const int hk = lane >> 5;         // k-half 0/1
    const int wr1 = w >> 2;           // wave px half (2 image rows each)
    const int wc32 = (w & 3) * 32;    // oc offset within 128-half
    const int sx = tid >> 3;                              // 0..63
    const int icsw = ((tid & 7) ^ ((tid >> 3) & 7)) * 8;  // pre-swizzled ic offset
    const unsigned short* zps = zp + icsw;
    const unsigned short* catb = cat + ((size_t)b * 4096) * 1024 + icsw;
    // fragment column offsets (shorts): physical = kcol[ks] ^ key(row)
    int kcol[4];
#pragma unroll
    for (int ks = 0; ks < 4; ++ks) kcol[ks] = ks * 16 + hk * 8;
    int keyd[3];
#pragma unroll
    for (int d = 0; d < 3; ++d) keyd[d] = ((l31 + d - 1) & 7) << 3;
    const int keyb = (l31 & 7) << 3;

    f32x16 acc[4][2];
#pragma unroll
    for (int rt = 0; rt < 4; ++rt)
#pragma unroll
        for (int ct = 0; ct < 2; ++ct)
#pragma unroll
            for (int j = 0; j < 16; ++j) acc[rt][ct][j] = 0.f;

    bf16x8 afr[2][2][4];  // [ks-pair][kk][row-tile]
    bf16x8 bq[2];
    const bf16x8 zf = {};

#define AF_PAIR(PAIR, DY, DX, DXI)                                                 \
    _Pragma("unroll") for (int rt_ = 0; rt_ < 4; ++rt_) {                          \
        const int r_ = wr1 * 2 + (rt_ >> 1) + (DY) + 1;                            \
        const int phys_ = (r_ < 2) ? r_ : r_ + 4 * cp;                             \
        int x_ = (rt_ & 1) * 32 + l31 + (DX);                                      \
        if ((DX) != 0) x_ = min(max(x_, 0), 63);                                   \
        const int ab_ = phys_ * 4096 + x_ * 64;                                    \
        _Pragma("unroll") for (int kk_ = 0; kk_ < 2; ++kk_)                        \
            afr[PAIR][kk_][rt_] = *(const bf16x8*)(As + ab_ +                      \
                (kcol[(PAIR) * 2 + kk_] ^ keyd[DXI]));                             \
        if ((DX) == -1 && (rt_ & 1) == 0 && l31 == 0) {                            \
            afr[PAIR][0][rt_] = zf; afr[PAIR][1][rt_] = zf; }                      \
        if ((DX) == 1 && (rt_ & 1) == 1 && l31 == 31) {                            \
            afr[PAIR][0][rt_] = zf; afr[PAIR][1][rt_] = zf; }                      \
    }

#define BQ_PAIR(SR, CT, PAIR)                                                      \
    _Pragma("unroll") for (int kk_ = 0; kk_ < 2; ++kk_)                            \
        bq[kk_] = *(const bf16x8*)(Bs + (SR) +                                     \
            ((CT) * 128 + wc32 + l31) * 64 + (kcol[(PAIR) * 2 + kk_] ^ keyb));

#define STAGE_BH(H, SWOFF, TAP, ICB)                                               \
    _Pragma("unroll") for (int j_ = 0; j_ < 2; ++j_) {                             \
        gload16(Bs + (SWOFF) + (H) * 8192 + (j_ * 512 + tid) * 8,                  \
                wt + (size_t)(TAP) * 524288 +                                      \
                    (size_t)(ocb + (H) * 128 + j_ * 64 + sx) * 1024 + (ICB) + icsw); \
    }

#define STAGE_AROW(R)                                                              \
    do {                                                                           \
        const int yy_ = y0 - 1 + (R);                                              \
        const int ph_ = ((R) < 2) ? (R) : (R) + 4 * cp1;                           \
        const unsigned short* s2_ = ((unsigned)yy_ < 64u)                          \
            ? catb + ((size_t)(yy_ * 64 + sx)) * 1024 + iccn : zps;                \
        gload16(As + ph_ * 4096 + tid * 8, s2_);                                   \
    } while (0)

#define MFMA8(PAIR, CT)                                                            \
    __builtin_amdgcn_s_setprio(1);                                                 \
    _Pragma("unroll") for (int kk_ = 0; kk_ < 2; ++kk_)                            \
        _Pragma("unroll") for (int rt_ = 0; rt_ < 4; ++rt_)                        \
            acc[rt_][CT] = __builtin_amdgcn_mfma_f32_32x32x16_bf16(                \
                afr[PAIR][kk_][rt_], bq[kk_], acc[rt_][CT], 0, 0, 0);              \
    __builtin_amdgcn_s_setprio(0);

#define VWAIT(N)                                                                   \
    asm volatile("s_waitcnt vmcnt(" #N ")" ::: "memory");                          \
    __builtin_amdgcn_sched_barrier(0);

#define TAP_BODY(T, DY, DX, DXI, AROW, W0N, W2N)                                   \
    {                                                                              \
        const int s_ = (c + (T)) & 1;                                              \
        const int sr_ = s_ << 14;                                                  \
        const int sw_ = sr_ ^ 16384;                                               \
        const int tn_ = ((T) == 8) ? 0 : (T) + 1;                                  \
        const int icb_ = ((T) == 8) ? iccn : icc;                                  \
        /* ph0: ks-pair0 x ct0 */                                                  \
        VWAIT(W0N)                                                                 \
        __builtin_amdgcn_s_barrier();                                              \
        __builtin_amdgcn_sched_barrier(0);                                         \
        AF_PAIR(0, DY, DX, DXI)                                                    \
        BQ_PAIR(sr_, 0, 0)                                                         \
        STAGE_BH(0, sw_, tn_, icb_)                                                \
        MFMA8(0, 0)                                                                \
        /* ph1: ks-pair1 x ct0 */                                                  \
        AF_PAIR(1, DY, DX, DXI)                                                    \
        BQ_PAIR(sr_, 0, 1)                                                         \
        if ((AROW) >= 0) STAGE_AROW(AROW);                                         \
        MFMA8(1, 0)                                                                \
        /* ph2: ks-pair0 x ct1 */                                                  \
        VWAIT(W2N)                                                                 \
        BQ_PAIR(sr_, 1, 0)                                                         \
        STAGE_BH(1, sw_, tn_, icb_)                                                \
        MFMA8(0, 1)                                                                \
        /* ph3: ks-pair1 x ct1 */                                                  \
        BQ_PAIR(sr_, 1, 1)                                                         \
        MFMA8(1, 1)                                                                \
    }

    // prologue: chunk 0 A-region (rows 0-5, parity 0) + B[0] both halves
    {
        const int cp1 = 0, iccn = 0;
#pragma unroll
        for (int r = 0; r < 6; ++r) STAGE_AROW(r);
    }
    STAGE_BH(0, 0, 0, 0)
    STAGE_BH(1, 0, 0, 0)

    for (int c = 0; c < 16; ++c) {
        const int cp = c & 1;
        const int cp1 = cp ^ 1;
        const int icc = c << 6;
        const int iccn = ((c + 1) & 15) << 6;
        TAP_BODY(0, -1, -1, 0, -1, 2, 2)
        TAP_BODY(1, -1, 0, 1, -1, 2, 2)
        TAP_BODY(2, -1, 1, 2, -1, 2, 2)
        TAP_BODY(3, 0, -1, 0, 0, 2, 3)
        TAP_BODY(4, 0, 0, 1, 2, 3, 3)
        TAP_BODY(5, 0, 1, 2, 3, 3, 3)
        TAP_BODY(6, 1, -1, 0, 1, 3, 3)
        TAP_BODY(7, 1, 0, 1, 4, 3, 3)
        TAP_BODY(8, 1, 1, 2, 5, 3, 3)
    }
    asm volatile("s_waitcnt vmcnt(0)" ::: "memory");

    // epilogue: affine + relu, f32 out.
    // C/D 32x32: col(oc)=l31, row(px-in-tile)=(reg&3)+8*(reg>>2)+4*hk
#pragma unroll
    for (int rt = 0; rt < 4; ++rt) {
        const int pxb = pix0 + (wr1 * 2 + (rt >> 1)) * 64 + (rt & 1) * 32 + hk * 4;
#pragma unroll
        for (int ct = 0; ct < 2; ++ct) {
            const int oc = ocb + ct * 128 + wc32 + l31;
            const float g = gamma[oc], bb = beta[oc];
            float* op = out + ((size_t)(b * 512 + oc)) * 4096 + pxb;
#pragma unroll
            for (int g2 = 0; g2 < 4; ++g2) {
                float4 o;
                o.x = fmaxf(fmaf(acc[rt][ct][g2 * 4 + 0], g, bb), 0.f);
                o.y = fmaxf(fmaf(acc[rt][ct][g2 * 4 + 1], g, bb), 0.f);
                o.z = fmaxf(fmaf(acc[rt][ct][g2 * 4 + 2], g, bb), 0.f);
                o.w = fmaxf(fmaf(acc[rt][ct][g2 * 4 + 3], g, bb), 0.f);
                *(float4*)(op + g2 * 8) = o;
            }
        }
    }
#undef AF_PAIR
#undef BQ_PAIR
#undef STAGE_BH
#undef STAGE_AROW
#undef MFMA8
#undef VWAIT
#undef TAP_BODY
}

// ---------------------------------------------------------------------------
extern "C" void kernel_launch(void* const* d_in, const int* in_sizes, int n_in,
                              void* d_out, int out_size, void* d_ws, size_t ws_size,
                              hipStream_t stream) {
    const float* x = (const float*)d_in[0];
    const float* dct = (const float*)d_in[1];
    const float* dm_w1 = (const float*)d_in[2];
    const float* dm_g = (const float*)d_in[3];
    const float* dm_b = (const float*)d_in[4];
    const float* dm_w2 = (const float*)d_in[5];
    const float* dm_b2 = (const float*)d_in[6];
    const float* fuse_w = (const float*)d_in[7];
    const float* fuse_b = (const float*)d_in[8];
    const float* gcn_w1 = (const float*)d_in[9];
    const float* gcn_w2 = (const float*)d_in[10];
    const float* bot_w = (const float*)d_in[11];
    const float* bot_g = (const float*)d_in[12];
    const float* bot_b = (const float*)d_in[13];

    float* y = (float*)d_out;
    float* out1 = y + (size_t)8 * 512 * 4096;
    // scratch in the y region (consumed by gcn/fuse_reduce before conv writes y)
    float* part = y;                     // 1,245,184 f32
    float* fpart = y + 1245184;          // 2,490,368 f32 (ends < 16.7M)

    char* ws = (char*)d_ws;
    const size_t CAT_BYTES = (size_t)8 * 4096 * 1024 * 2;     // 67108864
    const size_t WT_BYTES = (size_t)9 * 512 * 1024 * 2;       // 9437184
    const size_t PART_BYTES = (size_t)2048 * 152 * 4;         // (layout spacer)
    const size_t L2_BYTES = (size_t)8 * 9728 * 4;             // 311296
    const size_t ZP_BYTES = 4096;
    if (ws_size < CAT_BYTES + WT_BYTES + PART_BYTES + L2_BYTES + ZP_BYTES) return;

    unsigned short* cat = (unsigned short*)ws;
    unsigned short* wt = (unsigned short*)(ws + CAT_BYTES);
    float* local2 = (float*)(ws + CAT_BYTES + WT_BYTES + PART_BYTES);
    unsigned short* zp = (unsigned short*)(ws + CAT_BYTES + WT_BYTES + PART_BYTES + L2_BYTES);

    hipMemsetAsync(zp, 0, ZP_BYTES, stream);
    front_kernel<<<dim3(512), dim3(256), 0, stream>>>(x, dct, dm_w1, dm_g, dm_b,
                                                      dm_w2, dm_b2, fuse_w,
                                                      part, fpart, cat);
    fuse_reduce<<<dim3(2432), dim3(256), 0, stream>>>(fpart, fuse_b, out1);
    gcn_kernel<<<dim3(8), dim3(256), 0, stream>>>(part, gcn_w1, gcn_w2, local2);
    repack_w<<<dim3(512), dim3(256), 0, stream>>>(bot_w, wt);
    attn_kernel<<<dim3(512), dim3(256), 0, stream>>>(x, local2, cat);
    conv_kernel<<<dim3(256), dim3(512), 0, stream>>>(cat, wt, zp, bot_g, bot_b, y);
}

// Round 8
// 396.076 us; speedup vs baseline: 1.1862x; 1.1862x over previous
//
#include <hip/hip_runtime.h>

// Problem constants
// B=8, C=512, H=W=64, HW=4096, NUM=64, CG=8, NC=19, OUT=512, ICAT=1024

typedef __attribute__((ext_vector_type(8))) unsigned short u16x8;
typedef __attribute__((ext_vector_type(8))) __bf16 bf16x8;
typedef __attribute__((ext_vector_type(4))) float f32x4;

__device__ inline unsigned short f2bf(float f) {
    unsigned int u = __float_as_uint(f);
    u += 0x7fffu + ((u >> 16) & 1u);
    return (unsigned short)(u >> 16);
}

__device__ __forceinline__ void gload16(unsigned short* lds, const unsigned short* g) {
    __builtin_amdgcn_global_load_lds(
        (const __attribute__((address_space(1))) unsigned int*)g,
        (__attribute__((address_space(3))) unsigned int*)lds, 16, 0, 0);
}

// ---------------------------------------------------------------------------
// Repack bot_w [512][1024][3][3] f32 -> wt[tap][oc][ic] bf16.
// ---------------------------------------------------------------------------
__global__ __launch_bounds__(256) void repack_w(const float* __restrict__ w,
                                                unsigned short* __restrict__ wt) {
    __shared__ float buf[9216];
    const int oc = blockIdx.x;  // 512
    const int tid = threadIdx.x;
    const float* src = w + (size_t)oc * 9216;
    for (int i = tid; i < 9216; i += 256) buf[i] = src[i];
    __syncthreads();
#pragma unroll
    for (int t = 0; t < 9; ++t) {
        for (int i = tid; i < 1024; i += 256)
            wt[((size_t)t * 512 + oc) * 1024 + i] = f2bf(buf[i * 9 + t]);
    }
}

// ---------------------------------------------------------------------------
// front: fused decoder_map + fuse-partial + local-partial + x->bf16 cat.
// ---------------------------------------------------------------------------
__global__ __launch_bounds__(256) void front_kernel(
    const float* __restrict__ x, const float* __restrict__ dct,
    const float* __restrict__ w1, const float* __restrict__ gamma,
    const float* __restrict__ beta, const float* __restrict__ w2,
    const float* __restrict__ b2, const float* __restrict__ fuse_w,
    float* __restrict__ part, float* __restrict__ fpart,
    unsigned short* __restrict__ cat) {
    __shared__ __align__(16) float fgs[8][260];
    __shared__ __align__(16) float fms[19][260];
    __shared__ float sw1[64], sw2[152], sb2[19], sg[8], sb[8], sfw[64];
    const int bid = blockIdx.x;
    const int sp = bid >> 7;
    const int b = (bid >> 4) & 7;
    const int ch = bid & 15;
    const int tid = threadIdx.x;
    if (tid < 64) { sw1[tid] = w1[tid]; sfw[tid] = fuse_w[tid]; }
    if (tid < 152) sw2[tid] = w2[tid];
    if (tid < 19) sb2[tid] = b2[tid];
    if (tid < 8) { sg[tid] = gamma[tid]; sb[tid] = beta[tid]; }
    __syncthreads();
    const int p = ch * 256 + tid;
    const int kk = tid >> 3, cc = tid & 7;
    float facc[19];
#pragma unroll
    for (int k = 0; k < 19; ++k) facc[k] = 0.f;
    for (int nn = 0; nn < 16; ++nn) {
        const int n = sp * 16 + nn;
        float fg[8];
        u16x8 xw;
#pragma unroll
        for (int c = 0; c < 8; ++c) {
            const float xv = x[((size_t)(b * 512 + n * 8 + c)) * 4096 + p];
            fg[c] = xv * dct[((size_t)(n * 8 + c)) * 4096 + p];
            xw[c] = f2bf(xv);
            fgs[c][tid] = fg[c];
        }
        *(u16x8*)(cat + ((size_t)(b * 4096) + p) * 1024 + n * 8) = xw;
        float h1[8];
#pragma unroll
        for (int d = 0; d < 8; ++d) {
            float s = 0.f;
#pragma unroll
            for (int c = 0; c < 8; ++c) s = fmaf(sw1[d * 8 + c], fg[c], s);
            h1[d] = fmaxf(fmaf(s, sg[d], sb[d]), 0.f);
        }
        const float fw = sfw[n];
#pragma unroll
        for (int k = 0; k < 19; ++k) {
            float s = sb2[k];
#pragma unroll
            for (int d = 0; d < 8; ++d) s = fmaf(sw2[k * 8 + d], h1[d], s);
            fms[k][tid] = s;
            facc[k] = fmaf(fw, s, facc[k]);
        }
        __syncthreads();
        if (tid < 152) {
            float accv = 0.f;
#pragma unroll 8
            for (int p4 = 0; p4 < 256; p4 += 4) {
                const float4 a = *(const float4*)&fms[kk][p4];
                const float4 g4 = *(const float4*)&fgs[cc][p4];
                accv += a.x * g4.x + a.y * g4.y + a.z * g4.z + a.w * g4.w;
            }
            part[((size_t)((b * 64 + n) * 16) + ch) * 152 + tid] = accv;
        }
        __syncthreads();
    }
#pragma unroll
    for (int k = 0; k < 19; ++k)
        fpart[((size_t)(sp * 8 + b) * 19 + k) * 4096 + p] = facc[k];
}

__global__ __launch_bounds__(256) void fuse_reduce(
    const float* __restrict__ fpart, const float* __restrict__ fuse_b,
    float* __restrict__ out1) {
    const int i = blockIdx.x * 256 + threadIdx.x;  // 622592 total
    float s = fuse_b[0];
#pragma unroll
    for (int sp = 0; sp < 4; ++sp) s += fpart[(size_t)sp * 622592 + i];
    out1[i] = s;
}

// ---------------------------------------------------------------------------
// lsum: L[bn][t] = sum over 16 chunk-partials
// ---------------------------------------------------------------------------
__global__ __launch_bounds__(256) void lsum_kernel(
    const float* __restrict__ part, float* __restrict__ L) {
    const int i = blockIdx.x * 256 + threadIdx.x;  // 77824 = 304*256
    const int bn = i / 152;
    const int t = i - bn * 152;
    float s = 0.f;
#pragma unroll
    for (int ch = 0; ch < 16; ++ch)
        s += part[((size_t)(bn * 16 + ch)) * 152 + t];
    L[i] = s;
}

// ---------------------------------------------------------------------------
// gcn2: 64 blocks = (b, n-group of 8).  R = relu(w1@L + L); local2 = R@w2^T
// ---------------------------------------------------------------------------
__global__ __launch_bounds__(256) void gcn2_kernel(
    const float* __restrict__ Lg, const float* __restrict__ w1,
    const float* __restrict__ w2, float* __restrict__ local2) {
    __shared__ float L[9728];
    __shared__ float R[1216];
    __shared__ float sw1[4096];
    __shared__ float sw2[64];
    const int b = blockIdx.x >> 3;
    const int n0 = (blockIdx.x & 7) * 8;
    const int tid = threadIdx.x;
    for (int i = tid; i < 9728; i += 256) L[i] = Lg[(size_t)b * 9728 + i];
    for (int i = tid; i < 4096; i += 256) sw1[i] = w1[i];
    if (tid < 64) sw2[tid] = w2[tid];
    __syncthreads();
    for (int i = tid; i < 1216; i += 256) {
        const int nn = i / 152, t = i - nn * 152;
        const int m = n0 + nn;
        float g = 0.f;
        for (int n = 0; n < 64; ++n) g = fmaf(sw1[m * 64 + n], L[n * 152 + t], g);
        R[i] = fmaxf(g + L[m * 152 + t], 0.f);
    }
    __syncthreads();
    for (int i = tid; i < 1216; i += 256) {
        const int nn = i / 152, t = i - nn * 152;
        const int k = t >> 3, d = t & 7;
        float s = 0.f;
#pragma unroll
        for (int c = 0; c < 8; ++c) s = fmaf(R[nn * 152 + k * 8 + c], sw2[d * 8 + c], s);
        local2[(size_t)b * 9728 + (n0 + nn) * 152 + t] = s;
    }
}

// ---------------------------------------------------------------------------
// attention: per (b,n): softmax(x@L^T)@L -> cat upper half bf16
// ---------------------------------------------------------------------------
__global__ __launch_bounds__(256) void attn_kernel(
    const float* __restrict__ x, const float* __restrict__ local2,
    unsigned short* __restrict__ cat) {
    __shared__ float L[152];
    const int bn = blockIdx.x;  // 512
    const int b = bn >> 6, n = bn & 63;
    const int tid = threadIdx.x;
    if (tid < 152) L[tid] = local2[(size_t)bn * 152 + tid];
    __syncthreads();
    for (int i = 0; i < 16; ++i) {
        const int p = i * 256 + tid;
        float xv[8];
#pragma unroll
        for (int c = 0; c < 8; ++c)
            xv[c] = x[((size_t)(b * 512 + n * 8 + c)) * 4096 + p];
        float lg[19];
        float mx = -1e30f;
#pragma unroll
        for (int k = 0; k < 19; ++k) {
            float s = 0.f;
#pragma unroll
            for (int c = 0; c < 8; ++c) s = fmaf(xv[c], L[k * 8 + c], s);
            lg[k] = s;
            mx = fmaxf(mx, s);
        }
        float se = 0.f;
#pragma unroll
        for (int k = 0; k < 19; ++k) {
            lg[k] = __expf(lg[k] - mx);
            se += lg[k];
        }
        const float inv = 1.f / se;
        float ov[8];
#pragma unroll
        for (int c = 0; c < 8; ++c) ov[c] = 0.f;
#pragma unroll
        for (int k = 0; k < 19; ++k) {
#pragma unroll
            for (int c = 0; c < 8; ++c) ov[c] = fmaf(lg[k], L[k * 8 + c], ov[c]);
        }
        u16x8 w;
#pragma unroll
        for (int c = 0; c < 8; ++c) w[c] = f2bf(ov[c] * inv);
        *(u16x8*)(cat + ((size_t)(b * 4096) + p) * 1024 + 512 + n * 8) = w;
    }
}

// ---------------------------------------------------------------------------
// conv 3x3 SAME implicit GEMM, ic-major A-reuse (validated r6 structure:
// same staging, same vmcnt ledger, same swizzle, 1 barrier/tap).  Change vs
// r6: both A-fragment sets (af0/af1) stay register-resident, phases ordered
// q(0,0)->q(1,0)->q(1,1)->q(0,1) -> LDS reads 40 -> 24 b128/wave/tap.
// LDS: A 80KB + B 64KB = 144KB.
// ---------------------------------------------------------------------------
__global__ __launch_bounds__(512, 1) void conv_kernel(
    const unsigned short* __restrict__ cat, const unsigned short* __restrict__ wt,
    const unsigned short* __restrict__ zp,
    const float* __restrict__ gamma, const float* __restrict__ beta,
    float* __restrict__ out) {
    __shared__ __align__(16) unsigned short As[10 * 4096];  // 10 row-slots x 8KB
    __shared__ __align__(16) unsigned short Bs[2 * 16384];  // 2 slots x 32KB
    const int bid0 = blockIdx.x;                    // 256 blocks
    const int bid = (bid0 & 7) * 32 + (bid0 >> 3);  // XCD swizzle (bijective)
    const int mt = bid >> 1;                        // 128 M-tiles
    const int nt = bid & 1;                         // 2 N-tiles
    const int b = mt >> 4;
    const int pix0 = (mt & 15) * 256;
    const int y0 = (mt & 15) * 4;
    const int ocb = nt * 256;
    const int tid = threadIdx.x;
    const int w = tid >> 6;
    const int lane = tid & 63;
    const int l16 = lane & 15;
    const int khalf = lane >> 4;
    const int wr1 = w >> 2;           // wave row group 0/1
    const int wrow = wr1 * 64;
    const int wcol = (w & 3) * 32;
    const int sx = tid >> 3;                              // 0..63
    const int icsw = ((tid & 7) ^ ((tid >> 3) & 7)) * 8;  // pre-swizzled ic offset
    const unsigned short* zps = zp + icsw;
    const unsigned short* catb = cat + ((size_t)b * 4096) * 1024 + icsw;
    // swizzled column offsets (shorts) per dx in {-1,0,1}
    int colk[3][2];
#pragma unroll
    for (int d = 0; d < 3; ++d)
#pragma unroll
        for (int ks = 0; ks < 2; ++ks)
            colk[d][ks] = ((ks * 64 + khalf * 16) ^ (((l16 + d - 1) & 7) << 4)) >> 1;

    f32x4 acc[2][2][4][2];
#pragma unroll
    for (int qm = 0; qm < 2; ++qm)
#pragma unroll
        for (int qn = 0; qn < 2; ++qn)
#pragma unroll
            for (int m = 0; m < 4; ++m)
#pragma unroll
                for (int n = 0; n < 2; ++n)
#pragma unroll
                    for (int j = 0; j < 4; ++j) acc[qm][qn][m][n][j] = 0.f;

    bf16x8 af0[4][2];
    bf16x8 af1[4][2];
    bf16x8 bq[2][2];
    const bf16x8 zf = {};

#define AF_READ(AFD, QM, DY, DX)                                                   \
    {                                                                              \
        const int r_ = (QM) * 2 + wr1 + (DY) + 1;                                  \
        const int phys_ = (r_ < 2) ? r_ : r_ + 4 * cp;                             \
        const int rb_ = phys_ * 4096;                                              \
        _Pragma("unroll") for (int m_ = 0; m_ < 4; ++m_) {                         \
            const int xm_ = m_ * 16 + l16 + (DX);                                  \
            const int xc_ = ((DX) == 0) ? xm_ : min(max(xm_, 0), 63);              \
            const int ab_ = rb_ + xc_ * 64;                                        \
            _Pragma("unroll") for (int ks_ = 0; ks_ < 2; ++ks_)                    \
                AFD[m_][ks_] = *(const bf16x8*)(As + ab_ + colk[(DX) + 1][ks_]);   \
            if ((DX) == -1 && m_ == 0 && l16 == 0) { AFD[0][0] = zf; AFD[0][1] = zf; } \
            if ((DX) == 1 && m_ == 3 && l16 == 15) { AFD[3][0] = zf; AFD[3][1] = zf; } \
        }                                                                          \
    }

#define BQ_READ(SOFF, QN)                                                          \
    _Pragma("unroll") for (int n_ = 0; n_ < 2; ++n_)                               \
        _Pragma("unroll") for (int ks_ = 0; ks_ < 2; ++ks_)                        \
            bq[n_][ks_] = *(const bf16x8*)(Bs + (SOFF) +                           \
                ((QN) * 128 + wcol + n_ * 16 + l16) * 64 + colk[1][ks_]);

#define STAGE_BH(H, SWOFF, TAP, ICB)                                               \
    _Pragma("unroll") for (int j_ = 0; j_ < 2; ++j_) {                             \
        gload16(Bs + (SWOFF) + (H) * 8192 + (j_ * 512 + tid) * 8,                  \
                wt + (size_t)(TAP) * 524288 +                                      \
                    (size_t)(ocb + (H) * 128 + j_ * 64 + sx) * 1024 + (ICB) + icsw); \
    }

#define STAGE_AROW(R)                                                              \
    do {                                                                           \
        const int yy_ = y0 - 1 + (R);                                              \
        const int ph_ = ((R) < 2) ? (R) : (R) + 4 * cp1;                           \
        const unsigned short* s2_ = ((unsigned)yy_ < 64u)                          \
            ? catb + ((size_t)(yy_ * 64 + sx)) * 1024 + iccn : zps;                \
        gload16(As + ph_ * 4096 + tid * 8, s2_);                                   \
    } while (0)

#define MFMA_Q(AFD, QM, QN)                                                        \
    __builtin_amdgcn_s_setprio(1);                                                 \
    _Pragma("unroll") for (int m_ = 0; m_ < 4; ++m_)                               \
        _Pragma("unroll") for (int n_ = 0; n_ < 2; ++n_)                           \
            _Pragma("unroll") for (int ks_ = 0; ks_ < 2; ++ks_)                    \
                acc[QM][QN][m_][n_] = __builtin_amdgcn_mfma_f32_16x16x32_bf16(     \
                    AFD[m_][ks_], bq[n_][ks_], acc[QM][QN][m_][n_], 0, 0, 0);      \
    __builtin_amdgcn_s_setprio(0);

#define VWAIT(N)                                                                   \
    asm volatile("s_waitcnt vmcnt(" #N ")" ::: "memory");                          \
    __builtin_amdgcn_sched_barrier(0);

#define TAP_BODY(T, DY, DX, AROW, W0N, W2N)                                        \
    {                                                                              \
        const int s_ = (c + (T)) & 1;                                              \
        const int sr_ = s_ << 14;                                                  \
        const int sw_ = sr_ ^ 16384;                                               \
        const int tn_ = ((T) == 8) ? 0 : (T) + 1;                                  \
        const int icb_ = ((T) == 8) ? iccn : icc;                                  \
        /* ph0: q(0,0) */                                                          \
        VWAIT(W0N)                                                                 \
        __builtin_amdgcn_s_barrier();                                              \
        __builtin_amdgcn_sched_barrier(0);                                         \
        AF_READ(af0, 0, DY, DX)                                                    \
        BQ_READ(sr_, 0)                                                            \
        STAGE_BH(0, sw_, tn_, icb_)                                                \
        MFMA_Q(af0, 0, 0)                                                          \
        /* ph1: q(1,0) */                                                          \
        AF_READ(af1, 1, DY, DX)                                                    \
        if ((AROW) >= 0) STAGE_AROW(AROW);                                         \
        MFMA_Q(af1, 1, 0)                                                          \
        /* ph2: q(1,1) */                                                          \
        VWAIT(W2N)                                                                 \
        BQ_READ(sr_, 1)                                                            \
        STAGE_BH(1, sw_, tn_, icb_)                                                \
        MFMA_Q(af1, 1, 1)                                                          \
        /* ph3: q(0,1) — af0 still resident */                                     \
        MFMA_Q(af0, 0, 1)                                                          \
    }

    // prologue: chunk 0 A-region (rows 0-5, parity 0) + B[0] both halves
    {
        const int cp1 = 0, iccn = 0;
#pragma unroll
        for (int r = 0; r < 6; ++r) STAGE_AROW(r);
    }
    STAGE_BH(0, 0, 0, 0)
    STAGE_BH(1, 0, 0, 0)

    for (int c = 0; c < 16; ++c) {
        const int cp = c & 1;
        const int cp1 = cp ^ 1;
        const int icc = c << 6;
        const int iccn = ((c + 1) & 15) << 6;
        TAP_BODY(0, -1, -1, -1, 2, 2)
        TAP_BODY(1, -1, 0, -1, 2, 2)
        TAP_BODY(2, -1, 1, -1, 2, 2)
        TAP_BODY(3, 0, -1, 0, 2, 3)
        TAP_BODY(4, 0, 0, 2, 3, 3)
        TAP_BODY(5, 0, 1, 3, 3, 3)
        TAP_BODY(6, 1, -1, 1, 3, 3)
        TAP_BODY(7, 1, 0, 4, 3, 3)
        TAP_BODY(8, 1, 1, 5, 3, 3)
    }
    asm volatile("s_waitcnt vmcnt(0)" ::: "memory");

    // epilogue: affine + relu, f32 out.  C/D: col(oc)=l16, row=khalf*4+j
#pragma unroll
    for (int qn = 0; qn < 2; ++qn)
#pragma unroll
        for (int n = 0; n < 2; ++n) {
            const int oc = ocb + qn * 128 + wcol + n * 16 + l16;
            const float g = gamma[oc], bb = beta[oc];
#pragma unroll
            for (int qm = 0; qm < 2; ++qm)
#pragma unroll
                for (int m = 0; m < 4; ++m) {
                    const int P = qm * 128 + wrow + m * 16 + khalf * 4;
                    float4 o;
                    o.x = fmaxf(fmaf(acc[qm][qn][m][n][0], g, bb), 0.f);
                    o.y = fmaxf(fmaf(acc[qm][qn][m][n][1], g, bb), 0.f);
                    o.z = fmaxf(fmaf(acc[qm][qn][m][n][2], g, bb), 0.f);
                    o.w = fmaxf(fmaf(acc[qm][qn][m][n][3], g, bb), 0.f);
                    *(float4*)(out + ((size_t)(b * 512 + oc)) * 4096 + pix0 + P) = o;
                }
        }
#undef AF_READ
#undef BQ_READ
#undef STAGE_BH
#undef STAGE_AROW
#undef MFMA_Q
#undef VWAIT
#undef TAP_BODY
}

// ---------------------------------------------------------------------------
extern "C" void kernel_launch(void* const* d_in, const int* in_sizes, int n_in,
                              void* d_out, int out_size, void* d_ws, size_t ws_size,
                              hipStream_t stream) {
    const float* x = (const float*)d_in[0];
    const float* dct = (const float*)d_in[1];
    const float* dm_w1 = (const float*)d_in[2];
    const float* dm_g = (const float*)d_in[3];
    const float* dm_b = (const float*)d_in[4];
    const float* dm_w2 = (const float*)d_in[5];
    const float* dm_b2 = (const float*)d_in[6];
    const float* fuse_w = (const float*)d_in[7];
    const float* fuse_b = (const float*)d_in[8];
    const float* gcn_w1 = (const float*)d_in[9];
    const float* gcn_w2 = (const float*)d_in[10];
    const float* bot_w = (const float*)d_in[11];
    const float* bot_g = (const float*)d_in[12];
    const float* bot_b = (const float*)d_in[13];

    float* y = (float*)d_out;
    float* out1 = y + (size_t)8 * 512 * 4096;
    // scratch in the y region (consumed before conv overwrites y)
    float* part = y;                     // 1,245,184 f32
    float* fpart = y + 1245184;          // 2,490,368 f32
    float* Lbuf = y + 3735552;           // 77,824 f32 (ends < 16.7M)

    char* ws = (char*)d_ws;
    const size_t CAT_BYTES = (size_t)8 * 4096 * 1024 * 2;     // 67108864
    const size_t WT_BYTES = (size_t)9 * 512 * 1024 * 2;       // 9437184
    const size_t PART_BYTES = (size_t)2048 * 152 * 4;         // (layout spacer)
    const size_t L2_BYTES = (size_t)8 * 9728 * 4;             // 311296
    const size_t ZP_BYTES = 4096;
    if (ws_size < CAT_BYTES + WT_BYTES + PART_BYTES + L2_BYTES + ZP_BYTES) return;

    unsigned short* cat = (unsigned short*)ws;
    unsigned short* wt = (unsigned short*)(ws + CAT_BYTES);
    float* local2 = (float*)(ws + CAT_BYTES + WT_BYTES + PART_BYTES);
    unsigned short* zp = (unsigned short*)(ws + CAT_BYTES + WT_BYTES + PART_BYTES + L2_BYTES);

    hipMemsetAsync(zp, 0, ZP_BYTES, stream);
    front_kernel<<<dim3(512), dim3(256), 0, stream>>>(x, dct, dm_w1, dm_g, dm_b,
                                                      dm_w2, dm_b2, fuse_w,
                                                      part, fpart, cat);
    lsum_kernel<<<dim3(304), dim3(256), 0, stream>>>(part, Lbuf);
    gcn2_kernel<<<dim3(64), dim3(256), 0, stream>>>(Lbuf, gcn_w1, gcn_w2, local2);
    fuse_reduce<<<dim3(2432), dim3(256), 0, stream>>>(fpart, fuse_b, out1);
    repack_w<<<dim3(512), dim3(256), 0, stream>>>(bot_w, wt);
    attn_kernel<<<dim3(512), dim3(256), 0, stream>>>(x, local2, cat);
    conv_kernel<<<dim3(256), dim3(512), 0, stream>>>(cat, wt, zp, bot_g, bot_b, y);
}

// Round 9
// 393.832 us; speedup vs baseline: 1.1930x; 1.0057x over previous
//
#include <hip/hip_runtime.h>

// Problem constants
// B=8, C=512, H=W=64, HW=4096, NUM=64, CG=8, NC=19, OUT=512, ICAT=1024

typedef __attribute__((ext_vector_type(8))) unsigned short u16x8;
typedef __attribute__((ext_vector_type(8))) __bf16 bf16x8;
typedef __attribute__((ext_vector_type(4))) float f32x4;

__device__ inline unsigned short f2bf(float f) {
    unsigned int u = __float_as_uint(f);
    u += 0x7fffu + ((u >> 16) & 1u);
    return (unsigned short)(u >> 16);
}

__device__ inline float bf2f(unsigned short u) {
    return __uint_as_float(((unsigned int)u) << 16);
}

__device__ __forceinline__ void gload16(unsigned short* lds, const unsigned short* g) {
    __builtin_amdgcn_global_load_lds(
        (const __attribute__((address_space(1))) unsigned int*)g,
        (__attribute__((address_space(3))) unsigned int*)lds, 16, 0, 0);
}

// ---------------------------------------------------------------------------
// Repack bot_w [512][1024][3][3] f32 -> wt[tap][oc][ic] bf16.
// ---------------------------------------------------------------------------
__global__ __launch_bounds__(256) void repack_w(const float* __restrict__ w,
                                                unsigned short* __restrict__ wt) {
    __shared__ float buf[9216];
    const int oc = blockIdx.x;  // 512
    const int tid = threadIdx.x;
    const float* src = w + (size_t)oc * 9216;
    for (int i = tid; i < 9216; i += 256) buf[i] = src[i];
    __syncthreads();
#pragma unroll
    for (int t = 0; t < 9; ++t) {
        for (int i = tid; i < 1024; i += 256)
            wt[((size_t)t * 512 + oc) * 1024 + i] = f2bf(buf[i * 9 + t]);
    }
}

// ---------------------------------------------------------------------------
// front: fused decoder_map + fuse-partial + local-partial + x->bf16 cat.
// ---------------------------------------------------------------------------
__global__ __launch_bounds__(256) void front_kernel(
    const float* __restrict__ x, const float* __restrict__ dct,
    const float* __restrict__ w1, const float* __restrict__ gamma,
    const float* __restrict__ beta, const float* __restrict__ w2,
    const float* __restrict__ b2, const float* __restrict__ fuse_w,
    float* __restrict__ part, float* __restrict__ fpart,
    unsigned short* __restrict__ cat) {
    __shared__ __align__(16) float fgs[8][260];
    __shared__ __align__(16) float fms[19][260];
    __shared__ float sw1[64], sw2[152], sb2[19], sg[8], sb[8], sfw[64];
    const int bid = blockIdx.x;
    const int sp = bid >> 7;
    const int b = (bid >> 4) & 7;
    const int ch = bid & 15;
    const int tid = threadIdx.x;
    if (tid < 64) { sw1[tid] = w1[tid]; sfw[tid] = fuse_w[tid]; }
    if (tid < 152) sw2[tid] = w2[tid];
    if (tid < 19) sb2[tid] = b2[tid];
    if (tid < 8) { sg[tid] = gamma[tid]; sb[tid] = beta[tid]; }
    __syncthreads();
    const int p = ch * 256 + tid;
    const int kk = tid >> 3, cc = tid & 7;
    float facc[19];
#pragma unroll
    for (int k = 0; k < 19; ++k) facc[k] = 0.f;
    for (int nn = 0; nn < 16; ++nn) {
        const int n = sp * 16 + nn;
        float fg[8];
        u16x8 xw;
#pragma unroll
        for (int c = 0; c < 8; ++c) {
            const float xv = x[((size_t)(b * 512 + n * 8 + c)) * 4096 + p];
            fg[c] = xv * dct[((size_t)(n * 8 + c)) * 4096 + p];
            xw[c] = f2bf(xv);
            fgs[c][tid] = fg[c];
        }
        *(u16x8*)(cat + ((size_t)(b * 4096) + p) * 1024 + n * 8) = xw;
        float h1[8];
#pragma unroll
        for (int d = 0; d < 8; ++d) {
            float s = 0.f;
#pragma unroll
            for (int c = 0; c < 8; ++c) s = fmaf(sw1[d * 8 + c], fg[c], s);
            h1[d] = fmaxf(fmaf(s, sg[d], sb[d]), 0.f);
        }
        const float fw = sfw[n];
#pragma unroll
        for (int k = 0; k < 19; ++k) {
            float s = sb2[k];
#pragma unroll
            for (int d = 0; d < 8; ++d) s = fmaf(sw2[k * 8 + d], h1[d], s);
            fms[k][tid] = s;
            facc[k] = fmaf(fw, s, facc[k]);
        }
        __syncthreads();
        if (tid < 152) {
            float accv = 0.f;
#pragma unroll 8
            for (int p4 = 0; p4 < 256; p4 += 4) {
                const float4 a = *(const float4*)&fms[kk][p4];
                const float4 g4 = *(const float4*)&fgs[cc][p4];
                accv += a.x * g4.x + a.y * g4.y + a.z * g4.z + a.w * g4.w;
            }
            part[((size_t)((b * 64 + n) * 16) + ch) * 152 + tid] = accv;
        }
        __syncthreads();
    }
#pragma unroll
    for (int k = 0; k < 19; ++k)
        fpart[((size_t)(sp * 8 + b) * 19 + k) * 4096 + p] = facc[k];
}

__global__ __launch_bounds__(256) void fuse_reduce(
    const float* __restrict__ fpart, const float* __restrict__ fuse_b,
    float* __restrict__ out1) {
    const int i = blockIdx.x * 256 + threadIdx.x;  // 622592 total
    float s = fuse_b[0];
#pragma unroll
    for (int sp = 0; sp < 4; ++sp) s += fpart[(size_t)sp * 622592 + i];
    out1[i] = s;
}

// ---------------------------------------------------------------------------
// lsum: L[bn][t] = sum over 16 chunk-partials
// ---------------------------------------------------------------------------
__global__ __launch_bounds__(256) void lsum_kernel(
    const float* __restrict__ part, float* __restrict__ L) {
    const int i = blockIdx.x * 256 + threadIdx.x;  // 77824 = 304*256
    const int bn = i / 152;
    const int t = i - bn * 152;
    float s = 0.f;
#pragma unroll
    for (int ch = 0; ch < 16; ++ch)
        s += part[((size_t)(bn * 16 + ch)) * 152 + t];
    L[i] = s;
}

// ---------------------------------------------------------------------------
// gcn2: 64 blocks = (b, n-group of 8).  R = relu(w1@L + L); local2 = R@w2^T
// ---------------------------------------------------------------------------
__global__ __launch_bounds__(256) void gcn2_kernel(
    const float* __restrict__ Lg, const float* __restrict__ w1,
    const float* __restrict__ w2, float* __restrict__ local2) {
    __shared__ float L[9728];
    __shared__ float R[1216];
    __shared__ float sw1[4096];
    __shared__ float sw2[64];
    const int b = blockIdx.x >> 3;
    const int n0 = (blockIdx.x & 7) * 8;
    const int tid = threadIdx.x;
    for (int i = tid; i < 9728; i += 256) L[i] = Lg[(size_t)b * 9728 + i];
    for (int i = tid; i < 4096; i += 256) sw1[i] = w1[i];
    if (tid < 64) sw2[tid] = w2[tid];
    __syncthreads();
    for (int i = tid; i < 1216; i += 256) {
        const int nn = i / 152, t = i - nn * 152;
        const int m = n0 + nn;
        float g = 0.f;
        for (int n = 0; n < 64; ++n) g = fmaf(sw1[m * 64 + n], L[n * 152 + t], g);
        R[i] = fmaxf(g + L[m * 152 + t], 0.f);
    }
    __syncthreads();
    for (int i = tid; i < 1216; i += 256) {
        const int nn = i / 152, t = i - nn * 152;
        const int k = t >> 3, d = t & 7;
        float s = 0.f;
#pragma unroll
        for (int c = 0; c < 8; ++c) s = fmaf(R[nn * 152 + k * 8 + c], sw2[d * 8 + c], s);
        local2[(size_t)b * 9728 + (n0 + nn) * 152 + t] = s;
    }
}

// ---------------------------------------------------------------------------
// attention: per (b,n): softmax(x@L^T)@L -> cat upper half bf16.
// x is read as bf16 from cat's LOWER half (written by front) — halves traffic.
// ---------------------------------------------------------------------------
__global__ __launch_bounds__(256) void attn_kernel(
    const float* __restrict__ local2, unsigned short* __restrict__ cat) {
    __shared__ float L[152];
    const int bn = blockIdx.x;  // 512
    const int b = bn >> 6, n = bn & 63;
    const int tid = threadIdx.x;
    if (tid < 152) L[tid] = local2[(size_t)bn * 152 + tid];
    __syncthreads();
    for (int i = 0; i < 16; ++i) {
        const int p = i * 256 + tid;
        const u16x8 xr = *(const u16x8*)(cat + ((size_t)(b * 4096) + p) * 1024 + n * 8);
        float xv[8];
#pragma unroll
        for (int c = 0; c < 8; ++c) xv[c] = bf2f(xr[c]);
        float lg[19];
        float mx = -1e30f;
#pragma unroll
        for (int k = 0; k < 19; ++k) {
            float s = 0.f;
#pragma unroll
            for (int c = 0; c < 8; ++c) s = fmaf(xv[c], L[k * 8 + c], s);
            lg[k] = s;
            mx = fmaxf(mx, s);
        }
        float se = 0.f;
#pragma unroll
        for (int k = 0; k < 19; ++k) {
            lg[k] = __expf(lg[k] - mx);
            se += lg[k];
        }
        const float inv = 1.f / se;
        float ov[8];
#pragma unroll
        for (int c = 0; c < 8; ++c) ov[c] = 0.f;
#pragma unroll
        for (int k = 0; k < 19; ++k) {
#pragma unroll
            for (int c = 0; c < 8; ++c) ov[c] = fmaf(lg[k], L[k * 8 + c], ov[c]);
        }
        u16x8 w;
#pragma unroll
        for (int c = 0; c < 8; ++c) w[c] = f2bf(ov[c] * inv);
        *(u16x8*)(cat + ((size_t)(b * 4096) + p) * 1024 + 512 + n * 8) = w;
    }
}

// ---------------------------------------------------------------------------
// conv 3x3 SAME implicit GEMM, ic-major K order with A-region reuse.
// VERBATIM the validated round-6 kernel (257 us, MfmaUtil 54%).
// Per 64-ic chunk: A-region staged once, 9 taps as LDS read offsets;
// B double-buffered; 4 phases/tap, ONE barrier/tap, counted vmcnt ledger.
// LDS: A 80KB + B 64KB = 144KB.
// ---------------------------------------------------------------------------
__global__ __launch_bounds__(512, 1) void conv_kernel(
    const unsigned short* __restrict__ cat, const unsigned short* __restrict__ wt,
    const unsigned short* __restrict__ zp,
    const float* __restrict__ gamma, const float* __restrict__ beta,
    float* __restrict__ out) {
    __shared__ __align__(16) unsigned short As[10 * 4096];  // 10 row-slots x 8KB
    __shared__ __align__(16) unsigned short Bs[2 * 16384];  // 2 slots x 32KB
    const int bid0 = blockIdx.x;                    // 256 blocks
    const int bid = (bid0 & 7) * 32 + (bid0 >> 3);  // XCD swizzle (bijective)
    const int mt = bid >> 1;                        // 128 M-tiles
    const int nt = bid & 1;                         // 2 N-tiles
    const int b = mt >> 4;
    const int pix0 = (mt & 15) * 256;
    const int y0 = (mt & 15) * 4;
    const int ocb = nt * 256;
    const int tid = threadIdx.x;
    const int w = tid >> 6;
    const int lane = tid & 63;
    const int l16 = lane & 15;
    const int khalf = lane >> 4;
    const int wr1 = w >> 2;           // wave row group 0/1
    const int wrow = wr1 * 64;
    const int wcol = (w & 3) * 32;
    const int sx = tid >> 3;                              // 0..63
    const int icsw = ((tid & 7) ^ ((tid >> 3) & 7)) * 8;  // pre-swizzled ic offset
    const unsigned short* zps = zp + icsw;
    const unsigned short* catb = cat + ((size_t)b * 4096) * 1024 + icsw;
    // swizzled column offsets (shorts) per dx in {-1,0,1}
    int colk[3][2];
#pragma unroll
    for (int d = 0; d < 3; ++d)
#pragma unroll
        for (int ks = 0; ks < 2; ++ks)
            colk[d][ks] = ((ks * 64 + khalf * 16) ^ (((l16 + d - 1) & 7) << 4)) >> 1;

    f32x4 acc[2][2][4][2];
#pragma unroll
    for (int qm = 0; qm < 2; ++qm)
#pragma unroll
        for (int qn = 0; qn < 2; ++qn)
#pragma unroll
            for (int m = 0; m < 4; ++m)
#pragma unroll
                for (int n = 0; n < 2; ++n)
#pragma unroll
                    for (int j = 0; j < 4; ++j) acc[qm][qn][m][n][j] = 0.f;

    bf16x8 af[4][2];
    bf16x8 bq[2][2];
    const bf16x8 zf = {};

#define AF_READ(QM, DY, DX)                                                        \
    {                                                                              \
        const int r_ = (QM) * 2 + wr1 + (DY) + 1;                                  \
        const int phys_ = (r_ < 2) ? r_ : r_ + 4 * cp;                             \
        const int rb_ = phys_ * 4096;                                              \
        _Pragma("unroll") for (int m_ = 0; m_ < 4; ++m_) {                         \
            const int xm_ = m_ * 16 + l16 + (DX);                                  \
            const int xc_ = ((DX) == 0) ? xm_ : min(max(xm_, 0), 63);              \
            const int ab_ = rb_ + xc_ * 64;                                        \
            _Pragma("unroll") for (int ks_ = 0; ks_ < 2; ++ks_)                    \
                af[m_][ks_] = *(const bf16x8*)(As + ab_ + colk[(DX) + 1][ks_]);    \
            if ((DX) == -1 && m_ == 0 && l16 == 0) { af[0][0] = zf; af[0][1] = zf; } \
            if ((DX) == 1 && m_ == 3 && l16 == 15) { af[3][0] = zf; af[3][1] = zf; } \
        }                                                                          \
    }

#define BQ_READ(SOFF, QN)                                                          \
    _Pragma("unroll") for (int n_ = 0; n_ < 2; ++n_)                               \
        _Pragma("unroll") for (int ks_ = 0; ks_ < 2; ++ks_)                        \
            bq[n_][ks_] = *(const bf16x8*)(Bs + (SOFF) +                           \
                ((QN) * 128 + wcol + n_ * 16 + l16) * 64 + colk[1][ks_]);

#define STAGE_BH(H, SWOFF, TAP, ICB)                                               \
    _Pragma("unroll") for (int j_ = 0; j_ < 2; ++j_) {                             \
        gload16(Bs + (SWOFF) + (H) * 8192 + (j_ * 512 + tid) * 8,                  \
                wt + (size_t)(TAP) * 524288 +                                      \
                    (size_t)(ocb + (H) * 128 + j_ * 64 + sx) * 1024 + (ICB) + icsw); \
    }

#define STAGE_AROW(R)                                                              \
    do {                                                                           \
        const int yy_ = y0 - 1 + (R);                                              \
        const int ph_ = ((R) < 2) ? (R) : (R) + 4 * cp1;                           \
        const unsigned short* s2_ = ((unsigned)yy_ < 64u)                          \
            ? catb + ((size_t)(yy_ * 64 + sx)) * 1024 + iccn : zps;                \
        gload16(As + ph_ * 4096 + tid * 8, s2_);                                   \
    } while (0)

#define MFMA_Q(QM, QN)                                                             \
    __builtin_amdgcn_s_setprio(1);                                                 \
    _Pragma("unroll") for (int m_ = 0; m_ < 4; ++m_)                               \
        _Pragma("unroll") for (int n_ = 0; n_ < 2; ++n_)                           \
            _Pragma("unroll") for (int ks_ = 0; ks_ < 2; ++ks_)                    \
                acc[QM][QN][m_][n_] = __builtin_amdgcn_mfma_f32_16x16x32_bf16(     \
                    af[m_][ks_], bq[n_][ks_], acc[QM][QN][m_][n_], 0, 0, 0);       \
    __builtin_amdgcn_s_setprio(0);

#define VWAIT(N)                                                                   \
    asm volatile("s_waitcnt vmcnt(" #N ")" ::: "memory");                          \
    __builtin_amdgcn_sched_barrier(0);

#define TAP_BODY(T, DY, DX, AROW, W0N, W2N)                                        \
    {                                                                              \
        const int s_ = (c + (T)) & 1;                                              \
        const int sr_ = s_ << 14;                                                  \
        const int sw_ = sr_ ^ 16384;                                               \
        const int tn_ = ((T) == 8) ? 0 : (T) + 1;                                  \
        const int icb_ = ((T) == 8) ? iccn : icc;                                  \
        /* ph0: q(0,0) */                                                          \
        VWAIT(W0N)                                                                 \
        __builtin_amdgcn_s_barrier();                                              \
        __builtin_amdgcn_sched_barrier(0);                                         \
        AF_READ(0, DY, DX)                                                         \
        BQ_READ(sr_, 0)                                                            \
        STAGE_BH(0, sw_, tn_, icb_)                                                \
        MFMA_Q(0, 0)                                                               \
        /* ph1: q(1,0) */                                                          \
        AF_READ(1, DY, DX)                                                         \
        if ((AROW) >= 0) STAGE_AROW(AROW);                                         \
        MFMA_Q(1, 0)                                                               \
        /* ph2: q(1,1) */                                                          \
        VWAIT(W2N)                                                                 \
        BQ_READ(sr_, 1)                                                            \
        STAGE_BH(1, sw_, tn_, icb_)                                                \
        MFMA_Q(1, 1)                                                               \
        /* ph3: q(0,1) */                                                          \
        AF_READ(0, DY, DX)                                                         \
        MFMA_Q(0, 1)                                                               \
    }

    // prologue: chunk 0 A-region (rows 0-5, parity 0) + B[0] both halves
    {
        const int cp1 = 0, iccn = 0;
#pragma unroll
        for (int r = 0; r < 6; ++r) STAGE_AROW(r);
    }
    STAGE_BH(0, 0, 0, 0)
    STAGE_BH(1, 0, 0, 0)

    for (int c = 0; c < 16; ++c) {
        const int cp = c & 1;
        const int cp1 = cp ^ 1;
        const int icc = c << 6;
        const int iccn = ((c + 1) & 15) << 6;
        TAP_BODY(0, -1, -1, -1, 2, 2)
        TAP_BODY(1, -1, 0, -1, 2, 2)
        TAP_BODY(2, -1, 1, -1, 2, 2)
        TAP_BODY(3, 0, -1, 0, 2, 3)
        TAP_BODY(4, 0, 0, 2, 3, 3)
        TAP_BODY(5, 0, 1, 3, 3, 3)
        TAP_BODY(6, 1, -1, 1, 3, 3)
        TAP_BODY(7, 1, 0, 4, 3, 3)
        TAP_BODY(8, 1, 1, 5, 3, 3)
    }
    asm volatile("s_waitcnt vmcnt(0)" ::: "memory");

    // epilogue: affine + relu, f32 out.  C/D: col(oc)=l16, row=khalf*4+j
#pragma unroll
    for (int qn = 0; qn < 2; ++qn)
#pragma unroll
        for (int n = 0; n < 2; ++n) {
            const int oc = ocb + qn * 128 + wcol + n * 16 + l16;
            const float g = gamma[oc], bb = beta[oc];
#pragma unroll
            for (int qm = 0; qm < 2; ++qm)
#pragma unroll
                for (int m = 0; m < 4; ++m) {
                    const int P = qm * 128 + wrow + m * 16 + khalf * 4;
                    float4 o;
                    o.x = fmaxf(fmaf(acc[qm][qn][m][n][0], g, bb), 0.f);
                    o.y = fmaxf(fmaf(acc[qm][qn][m][n][1], g, bb), 0.f);
                    o.z = fmaxf(fmaf(acc[qm][qn][m][n][2], g, bb), 0.f);
                    o.w = fmaxf(fmaf(acc[qm][qn][m][n][3], g, bb), 0.f);
                    *(float4*)(out + ((size_t)(b * 512 + oc)) * 4096 + pix0 + P) = o;
                }
        }
#undef AF_READ
#undef BQ_READ
#undef STAGE_BH
#undef STAGE_AROW
#undef MFMA_Q
#undef VWAIT
#undef TAP_BODY
}

// ---------------------------------------------------------------------------
extern "C" void kernel_launch(void* const* d_in, const int* in_sizes, int n_in,
                              void* d_out, int out_size, void* d_ws, size_t ws_size,
                              hipStream_t stream) {
    const float* x = (const float*)d_in[0];
    const float* dct = (const float*)d_in[1];
    const float* dm_w1 = (const float*)d_in[2];
    const float* dm_g = (const float*)d_in[3];
    const float* dm_b = (const float*)d_in[4];
    const float* dm_w2 = (const float*)d_in[5];
    const float* dm_b2 = (const float*)d_in[6];
    const float* fuse_w = (const float*)d_in[7];
    const float* fuse_b = (const float*)d_in[8];
    const float* gcn_w1 = (const float*)d_in[9];
    const float* gcn_w2 = (const float*)d_in[10];
    const float* bot_w = (const float*)d_in[11];
    const float* bot_g = (const float*)d_in[12];
    const float* bot_b = (const float*)d_in[13];

    float* y = (float*)d_out;
    float* out1 = y + (size_t)8 * 512 * 4096;
    // scratch in the y region (consumed before conv overwrites y)
    float* part = y;                     // 1,245,184 f32
    float* fpart = y + 1245184;          // 2,490,368 f32
    float* Lbuf = y + 3735552;           // 77,824 f32 (ends < 16.7M)

    char* ws = (char*)d_ws;
    const size_t CAT_BYTES = (size_t)8 * 4096 * 1024 * 2;     // 67108864
    const size_t WT_BYTES = (size_t)9 * 512 * 1024 * 2;       // 9437184
    const size_t PART_BYTES = (size_t)2048 * 152 * 4;         // (layout spacer)
    const size_t L2_BYTES = (size_t)8 * 9728 * 4;             // 311296
    const size_t ZP_BYTES = 4096;
    if (ws_size < CAT_BYTES + WT_BYTES + PART_BYTES + L2_BYTES + ZP_BYTES) return;

    unsigned short* cat = (unsigned short*)ws;
    unsigned short* wt = (unsigned short*)(ws + CAT_BYTES);
    float* local2 = (float*)(ws + CAT_BYTES + WT_BYTES + PART_BYTES);
    unsigned short* zp = (unsigned short*)(ws + CAT_BYTES + WT_BYTES + PART_BYTES + L2_BYTES);

    hipMemsetAsync(zp, 0, ZP_BYTES, stream);
    front_kernel<<<dim3(512), dim3(256), 0, stream>>>(x, dct, dm_w1, dm_g, dm_b,
                                                      dm_w2, dm_b2, fuse_w,
                                                      part, fpart, cat);
    lsum_kernel<<<dim3(304), dim3(256), 0, stream>>>(part, Lbuf);
    gcn2_kernel<<<dim3(64), dim3(256), 0, stream>>>(Lbuf, gcn_w1, gcn_w2, local2);
    fuse_reduce<<<dim3(2432), dim3(256), 0, stream>>>(fpart, fuse_b, out1);
    repack_w<<<dim3(512), dim3(256), 0, stream>>>(bot_w, wt);
    attn_kernel<<<dim3(512), dim3(256), 0, stream>>>(local2, cat);
    conv_kernel<<<dim3(256), dim3(512), 0, stream>>>(cat, wt, zp, bot_g, bot_b, y);
}